// Round 5
// baseline (814.111 us; speedup 1.0000x reference)
//
#include <hip/hip_runtime.h>
#include <cstdint>
#include <cstddef>

#define M_DIM 4096
#define N_DIM 16384
#define K_DIM 4096
#define NBLK_Q 128

#define BM 256
#define BN 256
#define BK 64
#define KTILES (K_DIM / BK)   // 64
#define NGROUPS (KTILES * 4)  // 256 16KB half-tile groups

typedef __bf16 bf16x8 __attribute__((ext_vector_type(8)));
typedef float f32x4 __attribute__((ext_vector_type(4)));
typedef unsigned short u16x8 __attribute__((ext_vector_type(8)));

__device__ __forceinline__ unsigned short f2bf(float f) {
  unsigned int u = __builtin_bit_cast(unsigned int, f);
  u += 0x7fffu + ((u >> 16) & 1u);
  return (unsigned short)(u >> 16);
}

__device__ __forceinline__ void async_copy16(const void* g, void* l) {
  __builtin_amdgcn_global_load_lds((__attribute__((address_space(1))) void*)g,
                                   (__attribute__((address_space(3))) void*)l,
                                   16, 0, 0);
}

// fence-ful barrier: identical HW semantics to __builtin_amdgcn_s_barrier but
// with a compiler memory clobber, so LDS reads/writes CANNOT be hoisted/sunk
// across it (the builtin is IntrNoMem in LLVM — plain loads can cross it).
// Deliberately does NOT drain vmcnt/lgkmcnt (counted-vmcnt pipeline).
#define BARRIER() asm volatile("s_barrier" ::: "memory")

// ---------------- pre-pass 1: x fp32 -> bf16 (A matrix [M][K]) ----------------
__global__ __launch_bounds__(256) void cvt_x_bf16(const float4* __restrict__ x,
                                                  ushort4* __restrict__ A) {
  int tid = blockIdx.x * 256 + threadIdx.x;
  float4 v = x[tid];
  ushort4 o;
  o.x = f2bf(v.x); o.y = f2bf(v.y); o.z = f2bf(v.z); o.w = f2bf(v.w);
  A[tid] = o;
}

// ------------- pre-pass 2: dequantize qs int32 + scales -> W bf16 [N][K] -------------
__global__ __launch_bounds__(256) void dequant_w(const int* __restrict__ qs,
                                                 const float* __restrict__ scales,
                                                 unsigned short* __restrict__ W) {
  size_t tid = (size_t)blockIdx.x * 256 + threadIdx.x;
  size_t e = tid * 8;
  size_t o = e >> 12;
  int nb = ((int)(e & 4095)) >> 5;
  float s = scales[o * NBLK_Q + nb];
  const int4* q = (const int4*)(qs + e);
  int4 q0 = q[0], q1 = q[1];
  u16x8 out;
  out[0] = f2bf(s * (float)q0.x);
  out[1] = f2bf(s * (float)q0.y);
  out[2] = f2bf(s * (float)q0.z);
  out[3] = f2bf(s * (float)q0.w);
  out[4] = f2bf(s * (float)q1.x);
  out[5] = f2bf(s * (float)q1.y);
  out[6] = f2bf(s * (float)q1.z);
  out[7] = f2bf(s * (float)q1.w);
  *(u16x8*)(W + e) = out;
}

// ---------------- main GEMM: C[M][N] = A[M][K] * Bt[N][K]^T + bias ----------------
// 256x256, BK=64, 8 waves (2Mx4N), per-wave 128x64, 16x16x32 MFMA, 4 phases/K-tile.
// Phase: {ds_read this phase's frags (pre-barrier — issues under prev phase's
// MFMA drain); stage; [vmcnt(2) at P3 only]; sched_barrier; BARRIER; setprio(1);
// 16 MFMA; setprio(0); BARRIER}. Counted vmcnt never 0 in the loop.
// Stage cadence is FIXED (clamped at the tail, duplicate stages rewrite
// identical bytes) so vmcnt(2) at P3 always means "tile kt+1 fully landed".
// LDS: 2 x 64KB fragment-contiguous buffers (1KB frags, 0 bank conflicts);
// groups g0=A.ks0 g1=A.ks1 g2=B.ks0 g3=B.ks1; wave w stages frags 2w,2w+1 of
// each group (wave-uniform LDS dest + lane*16, pre-swizzled global source).
__global__ __launch_bounds__(512, 2) void gemm_bt_bias(
    const unsigned short* __restrict__ A,   // [M][K] bf16
    const unsigned short* __restrict__ Bt,  // [N][K] bf16
    const float* __restrict__ bias,         // [N]
    float* __restrict__ C) {                // [M][N] fp32
  __shared__ char lds[131072];  // 2 x 64KB

  const int tid = threadIdx.x;
  const int w = tid >> 6;   // wave 0..7
  const int l = tid & 63;
  const int wm = w >> 2;    // M half
  const int wn = w & 3;     // N quarter
  const int sr = l & 15;
  const int sg = l >> 4;

  // XCD-chunked bijective grid mapping, mtile fastest
  const int bid = blockIdx.x;
  const int wgid = (bid & 7) * 128 + (bid >> 3);
  const int mtile = wgid & 15;
  const int ntile = wgid >> 4;
  const int brow = mtile * BM;
  const int bcol = ntile * BN;

  // precomputed per-thread staging bases (element offsets into A / Bt)
  const size_t offA = (size_t)(brow + (w * 2) * 16 + sr) * K_DIM + sg * 8;
  const size_t offB = (size_t)(bcol + (w * 2) * 16 + sr) * K_DIM + sg * 8;
  char* const ldsbase = lds + w * 2048 + l * 16;

  auto stage = [&](int q) {
    q = (q > NGROUPS - 1) ? (NGROUPS - 1) : q;  // clamp: fixed issue cadence
    const int kt_s = q >> 2;
    const int g = q & 3;
    const int kof = kt_s * BK + (g & 1) * 32;
    const unsigned short* src = (g < 2) ? (A + offA + kof) : (Bt + offB + kof);
    char* dst = ldsbase + (kt_s & 1) * 65536 + g * 16384;
    async_copy16(src, dst);
    async_copy16(src + 16 * K_DIM, dst + 1024);
  };

  f32x4 acc[8][4] = {};
  bf16x8 pa[2][4];  // A fragments for current ih-half (ks, i)
  bf16x8 b[2][4];   // B fragments for whole K-tile (ks, j)

  // prologue: stage tile0 g0-g3 + tile1 g0; wait tile0 (leave tile1.g0 in flight)
#pragma unroll
  for (int q = 0; q < 5; ++q) stage(q);
  asm volatile("s_waitcnt vmcnt(2)" ::: "memory");
  BARRIER();

  for (int kt = 0; kt < KTILES; ++kt) {
    const char* bb = lds + (kt & 1) * 65536;

    // ---- P0: quadrant (ih0, jh0) ----
#pragma unroll
    for (int s = 0; s < 2; ++s) {
#pragma unroll
      for (int i = 0; i < 4; ++i)
        pa[s][i] = *(const bf16x8*)(bb + (s * 16 + wm * 8 + i) * 1024 + l * 16);
#pragma unroll
      for (int j = 0; j < 2; ++j)
        b[s][j] = *(const bf16x8*)(bb + 32768 + (s * 16 + wn * 4 + j) * 1024 + l * 16);
    }
    stage(4 * kt + 5);
    stage(4 * kt + 6);
    __builtin_amdgcn_sched_barrier(0);
    BARRIER();
    __builtin_amdgcn_s_setprio(1);
#pragma unroll
    for (int i = 0; i < 4; ++i)
#pragma unroll
      for (int j = 0; j < 2; ++j) {
        acc[i][j] = __builtin_amdgcn_mfma_f32_16x16x32_bf16(pa[0][i], b[0][j], acc[i][j], 0, 0, 0);
        acc[i][j] = __builtin_amdgcn_mfma_f32_16x16x32_bf16(pa[1][i], b[1][j], acc[i][j], 0, 0, 0);
      }
    __builtin_amdgcn_s_setprio(0);
    BARRIER();

    // ---- P1: quadrant (ih0, jh1) ----
#pragma unroll
    for (int s = 0; s < 2; ++s)
#pragma unroll
      for (int j = 0; j < 2; ++j)
        b[s][2 + j] = *(const bf16x8*)(bb + 32768 + (s * 16 + wn * 4 + 2 + j) * 1024 + l * 16);
    stage(4 * kt + 7);
    __builtin_amdgcn_sched_barrier(0);
    BARRIER();
    __builtin_amdgcn_s_setprio(1);
#pragma unroll
    for (int i = 0; i < 4; ++i)
#pragma unroll
      for (int j = 0; j < 2; ++j) {
        acc[i][2 + j] = __builtin_amdgcn_mfma_f32_16x16x32_bf16(pa[0][i], b[0][2 + j], acc[i][2 + j], 0, 0, 0);
        acc[i][2 + j] = __builtin_amdgcn_mfma_f32_16x16x32_bf16(pa[1][i], b[1][2 + j], acc[i][2 + j], 0, 0, 0);
      }
    __builtin_amdgcn_s_setprio(0);
    BARRIER();

    // ---- P2: quadrant (ih1, jh0) ----
#pragma unroll
    for (int s = 0; s < 2; ++s)
#pragma unroll
      for (int i = 0; i < 4; ++i)
        pa[s][i] = *(const bf16x8*)(bb + (s * 16 + wm * 8 + 4 + i) * 1024 + l * 16);
    __builtin_amdgcn_sched_barrier(0);
    BARRIER();
    __builtin_amdgcn_s_setprio(1);
#pragma unroll
    for (int i = 0; i < 4; ++i)
#pragma unroll
      for (int j = 0; j < 2; ++j) {
        acc[4 + i][j] = __builtin_amdgcn_mfma_f32_16x16x32_bf16(pa[0][i], b[0][j], acc[4 + i][j], 0, 0, 0);
        acc[4 + i][j] = __builtin_amdgcn_mfma_f32_16x16x32_bf16(pa[1][i], b[1][j], acc[4 + i][j], 0, 0, 0);
      }
    __builtin_amdgcn_s_setprio(0);
    BARRIER();  // bar2(P2): all waves done reading this buffer's g0/g1

    // ---- P3: quadrant (ih1, jh1) ----
    stage(4 * kt + 8);  // tile kt+2 g0 -> current buffer; safe post bar2(P2)
    asm volatile("s_waitcnt vmcnt(2)" ::: "memory");  // tile kt+1 fully landed
    __builtin_amdgcn_sched_barrier(0);
    BARRIER();
    __builtin_amdgcn_s_setprio(1);
#pragma unroll
    for (int i = 0; i < 4; ++i)
#pragma unroll
      for (int j = 0; j < 2; ++j) {
        acc[4 + i][2 + j] = __builtin_amdgcn_mfma_f32_16x16x32_bf16(pa[0][i], b[0][2 + j], acc[4 + i][2 + j], 0, 0, 0);
        acc[4 + i][2 + j] = __builtin_amdgcn_mfma_f32_16x16x32_bf16(pa[1][i], b[1][2 + j], acc[4 + i][2 + j], 0, 0, 0);
      }
    __builtin_amdgcn_s_setprio(0);
    BARRIER();
  }

  asm volatile("s_waitcnt vmcnt(0)" ::: "memory");

  // epilogue: C/D layout col = lane&15, row = (lane>>4)*4 + t
#pragma unroll
  for (int j = 0; j < 4; ++j) {
    const int col = bcol + wn * 64 + j * 16 + sr;
    const float bv = bias[col];
#pragma unroll
    for (int i = 0; i < 8; ++i) {
      const int row = brow + wm * 128 + i * 16 + sg * 4;
#pragma unroll
      for (int t = 0; t < 4; ++t) {
        C[(size_t)(row + t) * N_DIM + col] = acc[i][j][t] + bv;
      }
    }
  }
}

// ---------------- fallback (ws too small): exact fp32, slow but correct ----------------
__global__ void naive_gemm(const float* __restrict__ x, const int* __restrict__ qs,
                           const float* __restrict__ scales, const float* __restrict__ bias,
                           float* __restrict__ y) {
  size_t idx = (size_t)blockIdx.x * 256 + threadIdx.x;
  if (idx >= (size_t)M_DIM * N_DIM) return;
  int o = (int)(idx % N_DIM);
  size_t m = idx / N_DIM;
  const float* xr = x + m * K_DIM;
  const int* q = qs + (size_t)o * K_DIM;
  const float* sc = scales + (size_t)o * NBLK_Q;
  float sum = 0.f;
  for (int nb = 0; nb < NBLK_Q; ++nb) {
    float s = sc[nb];
    float bs = 0.f;
#pragma unroll 8
    for (int b = 0; b < 32; ++b) bs += xr[nb * 32 + b] * (float)q[nb * 32 + b];
    sum += s * bs;
  }
  y[idx] = sum + bias[o];
}

extern "C" void kernel_launch(void* const* d_in, const int* in_sizes, int n_in,
                              void* d_out, int out_size, void* d_ws, size_t ws_size,
                              hipStream_t stream) {
  const float* x = (const float*)d_in[0];
  const int* qs = (const int*)d_in[1];
  const float* scales = (const float*)d_in[2];
  const float* bias = (const float*)d_in[3];
  float* y = (float*)d_out;

  const size_t A_bytes = (size_t)M_DIM * K_DIM * 2;  // 32 MB
  const size_t W_bytes = (size_t)N_DIM * K_DIM * 2;  // 128 MB

  if (ws_size < A_bytes + W_bytes) {
    size_t total = (size_t)M_DIM * N_DIM;
    naive_gemm<<<(unsigned)((total + 255) / 256), 256, 0, stream>>>(x, qs, scales, bias, y);
    return;
  }

  unsigned short* A = (unsigned short*)d_ws;
  unsigned short* W = (unsigned short*)((char*)d_ws + A_bytes);

  cvt_x_bf16<<<(M_DIM * K_DIM / 4) / 256, 256, 0, stream>>>((const float4*)x, (ushort4*)A);
  dequant_w<<<(int)(((size_t)N_DIM * K_DIM / 8) / 256), 256, 0, stream>>>(qs, scales, W);
  gemm_bt_bias<<<(M_DIM / BM) * (N_DIM / BN), 512, 0, stream>>>(A, W, bias, y);
}